// Round 6
// baseline (352.089 us; speedup 1.0000x reference)
//
#include <hip/hip_runtime.h>
#include <stdint.h>

// MultiHeadAttention  B=8, S=2048, D=768  (fp32 in/out; bf16 MFMA compute)
//
// Pipeline:
//   convert : all 9 fp32 inputs -> bf16 in ws
//   qkv_k   : fused Q/K/V projections (grid 128x18, tile 128x128); Vt[b][e][s]
//   score_k : E = exp(min(Q.K^T/sqrt(D),30)) bf16 + fused rowsum -> rl
//   pv_k    : attn = (E @ V) * rcp(rl)
//   out_k   : out = attn@Wp^T + bp  (fp32)
//
// *** R6 = R5 core with A-fragment address fix ***
// R5 failed correctness: aAr omitted the wave-row-half offset (wr*4096 B), so
// both wr waves read A rows 0..63 while the epilogue wrote rows wr*64+..
// (absmax 0.67 = rows 64-127 wrong in every tile). Fixed: aAr includes
// (wr*64+lo)*64. Core otherwise unchanged from R5:
// 256 thr (4 waves, 2Mx2N, wave=64x64, acc[4][4]); LDS 2x16 KB double-buffer;
// per K-tile {issue 4 global_load_lds for kt+1 -> 8 asm ds_reads -> 4 groups
// of {lgkmcnt(3-g); sched_barrier; 4 MFMA} -> one __syncthreads}. 4-slot XOR
// swizzle (2 lanes/bank = free). 4 blocks/CU = 4 independent barrier domains.

typedef __attribute__((ext_vector_type(8))) short short8;
typedef __attribute__((ext_vector_type(4))) float f32x4;

typedef const __attribute__((address_space(1))) void gvoid_t;
typedef __attribute__((address_space(3))) void lvoid_t;

__device__ __forceinline__ float b2f(unsigned short u) {
  union { unsigned int u; float f; } v;
  v.u = ((unsigned int)u) << 16;
  return v.f;
}
__device__ __forceinline__ unsigned short f2b(float f) {
  union { float f; unsigned int u; } v; v.f = f;
  unsigned int u = v.u;
  return (unsigned short)((u + 0x7fffu + ((u >> 16) & 1u)) >> 16);
}

// ---------------- fp32 -> bf16 conversion ----------------
struct Cvt9 {
  const void* s[9];
  unsigned short* d[9];
  long long n8[9];
  long long total8;
};

__global__ __launch_bounds__(256) void convert_inputs(Cvt9 C) {
  long long g = (long long)blockIdx.x * 256 + threadIdx.x;
  if (g >= C.total8) return;
  int s = 0;
  long long off = g;
  while (off >= C.n8[s]) { off -= C.n8[s]; ++s; }
  const float* sf = (const float*)C.s[s] + off * 8;
  unsigned short* dp = C.d[s] + off * 8;
  float4 a = ((const float4*)sf)[0];
  float4 b = ((const float4*)sf)[1];
  uint4 o;
  o.x = (unsigned int)f2b(a.x) | ((unsigned int)f2b(a.y) << 16);
  o.y = (unsigned int)f2b(a.z) | ((unsigned int)f2b(a.w) << 16);
  o.z = (unsigned int)f2b(b.x) | ((unsigned int)f2b(b.y) << 16);
  o.w = (unsigned int)f2b(b.z) | ((unsigned int)f2b(b.w) << 16);
  *(uint4*)dp = o;
}

// ---------------- 128x128 / BK=32 GEMM core (4 waves) ----------------
// C[m0..+128][n0..+128] += A[m0..][0..K) . B[n0..][0..K)^T  (both NT-major, bf16)
// LDS buf b at b*16384 B: A 128x32 bf16 (8192 B), B 128x32 (8192 B).
// 4 slots of 16B per row; slot swizzle: src slot = (t&3)^(row&3), read slot =
// quad^(row&3)  -> 2 lanes/bank-group (free).
__device__ __forceinline__ void gemm128(
    const unsigned short* __restrict__ Ag,   // pre-offset to (m0, 0), lda shorts
    const unsigned short* __restrict__ Bg,   // pre-offset to (n0, 0), ldb shorts
    const int lda, const int ldb, const int NT,
    unsigned short* lds, f32x4 (&acc)[4][4])
{
  const int t    = threadIdx.x;
  const int w    = t >> 6;
  const int lane = t & 63;
  const int lo   = lane & 15;
  const int quad = lane >> 4;
  const int wr   = w >> 1;          // 0..1 row half
  const int wc   = w & 1;           // 0..1 col half
  const int srow = t >> 2;          // staging row 0..63 per round
  const int ssw  = ((t & 3) ^ (srow & 3)) << 3;   // pre-swizzled src k-slot (shorts)

  const unsigned lbase = (unsigned)(uintptr_t)(void*)lds;
  const unsigned rsw   = (unsigned)((quad ^ (lo & 3)) << 4);   // read slot (bytes)
  // A row = wr*64 + mi*16 + lo  (row stride 64 B); FIX: wr*4096 was missing in R5
  const unsigned aAr   = lbase + (unsigned)(wr * 64 + lo) * 64 + rsw;           // + mi*1024
  const unsigned aBr   = lbase + 8192u + (unsigned)(wc * 64 + lo) * 64 + rsw;   // + ni*1024

#define STG(kt, buf) {                                                              \
  const unsigned short* a0_ = Ag + (size_t)(srow)      * lda + (kt) * 32 + ssw;     \
  const unsigned short* a1_ = Ag + (size_t)(64 + srow) * lda + (kt) * 32 + ssw;     \
  const unsigned short* b0_ = Bg + (size_t)(srow)      * ldb + (kt) * 32 + ssw;     \
  const unsigned short* b1_ = Bg + (size_t)(64 + srow) * ldb + (kt) * 32 + ssw;     \
  unsigned short* d_ = lds + (buf) * 8192 + t * 8;                                  \
  __builtin_amdgcn_global_load_lds((gvoid_t*)a0_, (lvoid_t*)(d_),        16, 0, 0); \
  __builtin_amdgcn_global_load_lds((gvoid_t*)a1_, (lvoid_t*)(d_ + 2048), 16, 0, 0); \
  __builtin_amdgcn_global_load_lds((gvoid_t*)b0_, (lvoid_t*)(d_ + 4096), 16, 0, 0); \
  __builtin_amdgcn_global_load_lds((gvoid_t*)b1_, (lvoid_t*)(d_ + 6144), 16, 0, 0); }
#define DSR(d, a, IMM) asm volatile("ds_read_b128 %0, %1 offset:" #IMM : "=v"(d) : "v"(a))
#define LGK(n) { asm volatile("s_waitcnt lgkmcnt(" #n ")" ::: "memory"); \
                 __builtin_amdgcn_sched_barrier(0); }
#define GRP(g) { _Pragma("unroll") for (int mi = 0; mi < 4; ++mi)             \
    acc[mi][g] = __builtin_amdgcn_mfma_f32_16x16x32_bf16(                     \
        af[mi], bf[g], acc[mi][g], 0, 0, 0); }

  // prologue: stage tile 0 into buf 0
  STG(0, 0);
  __syncthreads();

  for (int kt = 0; kt < NT; ++kt) {
    const int buf = kt & 1;
    if (kt + 1 < NT) STG(kt + 1, buf ^ 1);

    const unsigned bo = (unsigned)(buf * 16384);
    short8 af[4], bf[4];
    const unsigned aA = aAr + bo, aB = aBr + bo;
    DSR(af[0], aA, 0); DSR(af[1], aA, 1024); DSR(af[2], aA, 2048); DSR(af[3], aA, 3072);
    DSR(bf[0], aB, 0); DSR(bf[1], aB, 1024); DSR(bf[2], aB, 2048); DSR(bf[3], aB, 3072);

    __builtin_amdgcn_s_setprio(1);
    LGK(3); GRP(0);
    LGK(2); GRP(1);
    LGK(1); GRP(2);
    LGK(0); GRP(3);
    __builtin_amdgcn_s_setprio(0);

    __syncthreads();   // drains vmcnt (tile kt+1 staged) + lgkm; barrier
  }
#undef STG
#undef DSR
#undef LGK
#undef GRP
}

// ---------------- bf16 epilogue: 128x128 tile via LDS halves ----------------
// MODE 0: v += bias ; MODE 2: v = exp(min(v*scale,30)) [+rowsum] ; MODE 3: v *= rcp(rl[row])
template<int MODE>
__device__ __forceinline__ void epi_bf16(
    unsigned short* Ls, f32x4 (&acc)[4][4],
    const unsigned short* bias_n0, const float* rlbase, float scale,
    unsigned short* Cg, int ldc, float* rlout)
{
  const int t = threadIdx.x, w = t >> 6, lane = t & 63;
  const int lo = lane & 15, quad = lane >> 4, wr = w >> 1, wc = w & 1;
#pragma unroll
  for (int h = 0; h < 2; ++h) {
    __syncthreads();
    if (wr == h) {
      float bvv[4];
      if (MODE == 0) {
#pragma unroll
        for (int ni = 0; ni < 4; ++ni) bvv[ni] = b2f(bias_n0[wc * 64 + ni * 16 + lo]);
      }
#pragma unroll
      for (int mi = 0; mi < 4; ++mi) {
        const int r0 = mi * 16 + quad * 4;
        float rv[4];
        if (MODE == 3) {
#pragma unroll
          for (int r = 0; r < 4; ++r) rv[r] = __builtin_amdgcn_rcpf(rlbase[h * 64 + r0 + r]);
        }
#pragma unroll
        for (int ni = 0; ni < 4; ++ni) {
          const int col = wc * 64 + ni * 16 + lo;
#pragma unroll
          for (int r = 0; r < 4; ++r) {
            float v = acc[mi][ni][r];
            if (MODE == 0)      v += bvv[ni];
            else if (MODE == 2) v = __expf(fminf(v * scale, 30.f));
            else if (MODE == 3) v *= rv[r];
            Ls[(r0 + r) * 136 + col] = f2b(v);
          }
        }
      }
    }
    __syncthreads();
#pragma unroll
    for (int j = 0; j < 4; ++j) {
      const int u = j * 256 + t, row = u >> 4, c16 = (u & 15) * 8;
      *(uint4*)(Cg + (size_t)(h * 64 + row) * ldc + c16) = *(const uint4*)(Ls + row * 136 + c16);
    }
    if (MODE == 2) {
      // fused partial rowsum of this half from LDS (4 threads/row)
      const int row = t >> 2, seg = t & 3;
      const unsigned short* lr = Ls + row * 136 + seg * 32;
      float s = 0.f;
#pragma unroll
      for (int q4 = 0; q4 < 4; ++q4) {
        uint4 v = *(const uint4*)(lr + q4 * 8);
        unsigned int uu[4] = {v.x, v.y, v.z, v.w};
#pragma unroll
        for (int c = 0; c < 4; ++c)
          s += b2f((unsigned short)(uu[c] & 0xffffu)) + b2f((unsigned short)(uu[c] >> 16));
      }
      s += __shfl_xor(s, 1);
      s += __shfl_xor(s, 2);
      if (seg == 0) atomicAdd(rlout + h * 64 + row, s);
    }
  }
}

// ---------------- qkv: fused projections ----------------
__global__ __launch_bounds__(256, 4) void qkv_k(
    const unsigned short* __restrict__ xb,
    const unsigned short* __restrict__ Wq, const unsigned short* __restrict__ bq,
    const unsigned short* __restrict__ Wk, const unsigned short* __restrict__ bk,
    const unsigned short* __restrict__ Wv, const unsigned short* __restrict__ bv,
    unsigned short* __restrict__ qb, unsigned short* __restrict__ kb,
    unsigned short* __restrict__ vt)
{
  __shared__ unsigned short smem[16384];   // 32768 B
  const int sel = blockIdx.y / 6;
  const int n0  = (blockIdx.y % 6) * 128;
  const int m0  = blockIdx.x * 128;

  const unsigned short* W;
  const unsigned short* bi;
  if (sel == 0)      { W = Wq; bi = bq; }
  else if (sel == 1) { W = Wk; bi = bk; }
  else               { W = Wv; bi = bv; }

  f32x4 acc[4][4] = {};
  gemm128(xb + (size_t)m0 * 768, W + (size_t)n0 * 768, 768, 768, 24, smem, acc);

  if (sel < 2) {
    unsigned short* dst = (sel == 0 ? qb : kb) + (size_t)m0 * 768 + n0;
    epi_bf16<0>(smem, acc, bi + n0, nullptr, 0.f, dst, 768, nullptr);
    return;
  }

  // V: transposed epilogue into Vt[b][e][s]; 2 e-halves of 64, Ls [64][136]
  const int t = threadIdx.x, w = t >> 6, lane = t & 63;
  const int lo = lane & 15, quad = lane >> 4, wr = w >> 1, wc = w & 1;
  const int bb2 = m0 >> 11, sin = m0 & 2047;
  unsigned short* Ls = smem;
#pragma unroll
  for (int ec = 0; ec < 2; ++ec) {
    __syncthreads();
    if (wc == ec) {
#pragma unroll
      for (int ni = 0; ni < 4; ++ni) {
        const int el = ni * 16 + lo;
        const float bvv = b2f(bi[n0 + ec * 64 + el]);
#pragma unroll
        for (int mi = 0; mi < 4; ++mi) {
          const int srow2 = wr * 64 + mi * 16 + quad * 4;
          ushort4 pk;
          pk.x = f2b(acc[mi][ni][0] + bvv);
          pk.y = f2b(acc[mi][ni][1] + bvv);
          pk.z = f2b(acc[mi][ni][2] + bvv);
          pk.w = f2b(acc[mi][ni][3] + bvv);
          *(ushort4*)(Ls + el * 136 + srow2) = pk;
        }
      }
    }
    __syncthreads();
    unsigned short* Vb = vt + (size_t)bb2 * 1572864 + (size_t)(n0 + ec * 64) * 2048 + sin;
#pragma unroll
    for (int j = 0; j < 4; ++j) {
      const int u = j * 256 + t, e = u >> 4, s16 = (u & 15) * 8;
      *(uint4*)(Vb + (size_t)e * 2048 + s16) = *(const uint4*)(Ls + e * 136 + s16);
    }
  }
}

// ---------------- score: E = exp(QK^T/sqrt(D)) + fused rowsum ----------------
__global__ __launch_bounds__(256, 4) void score_k(
    const unsigned short* __restrict__ Q, const unsigned short* __restrict__ Kb,
    unsigned short* __restrict__ E, float* __restrict__ rl, float scale)
{
  __shared__ unsigned short smem[16384];
  const int m0 = blockIdx.x * 128, n0 = blockIdx.y * 128, bz = blockIdx.z;

  f32x4 acc[4][4] = {};
  gemm128(Q + (size_t)bz * 1572864 + (size_t)m0 * 768,
          Kb + (size_t)bz * 1572864 + (size_t)n0 * 768, 768, 768, 24, smem, acc);

  unsigned short* Eg = E + (size_t)bz * 4194304 + (size_t)m0 * 2048 + n0;
  epi_bf16<2>(smem, acc, nullptr, nullptr, scale, Eg, 2048, rl + bz * 2048 + m0);
}

// ---------------- pv: attn = (E @ V) * rcp(rowsum) ----------------
__global__ __launch_bounds__(256, 4) void pv_k(
    const unsigned short* __restrict__ E, const unsigned short* __restrict__ Vt,
    const float* __restrict__ rl, unsigned short* __restrict__ attn)
{
  __shared__ unsigned short smem[16384];
  const int m0 = blockIdx.x * 128, n0 = blockIdx.y * 128, bz = blockIdx.z;

  f32x4 acc[4][4] = {};
  gemm128(E + (size_t)bz * 4194304 + (size_t)m0 * 2048,
          Vt + (size_t)bz * 1572864 + (size_t)n0 * 2048, 2048, 2048, 64, smem, acc);

  const float* rlb = rl + bz * 2048 + m0;
  unsigned short* Cg = attn + (size_t)bz * 1572864 + (size_t)m0 * 768 + n0;
  epi_bf16<3>(smem, acc, nullptr, rlb, 0.f, Cg, 768, nullptr);
}

// ---------------- out: final projection (fp32 output) ----------------
__global__ __launch_bounds__(256, 4) void out_k(
    const unsigned short* __restrict__ attn,
    const unsigned short* __restrict__ Wp, const unsigned short* __restrict__ bp,
    float* __restrict__ Of)
{
  __shared__ unsigned short smem[16384];
  const int m0 = blockIdx.x * 128, n0 = blockIdx.y * 128;

  f32x4 acc[4][4] = {};
  gemm128(attn + (size_t)m0 * 768, Wp + (size_t)n0 * 768, 768, 768, 24, smem, acc);

  // fp32 output: 4 passes of 32 rows staged as float through LDS [32][132]
  const int t = threadIdx.x, w = t >> 6, lane = t & 63;
  const int lo = lane & 15, quad = lane >> 4, wr = w >> 1, wc = w & 1;
  float* Lf = (float*)smem;
#pragma unroll
  for (int p = 0; p < 4; ++p) {
    __syncthreads();
    if (wr == (p >> 1)) {
#pragma unroll
      for (int mm = 0; mm < 2; ++mm) {
        const int mi = (p & 1) * 2 + mm;
        const int lr0 = mm * 16 + quad * 4;
#pragma unroll
        for (int ni = 0; ni < 4; ++ni) {
          const int col = wc * 64 + ni * 16 + lo;
          const float bvv = b2f(bp[n0 + col]);
#pragma unroll
          for (int r = 0; r < 4; ++r)
            Lf[(lr0 + r) * 132 + col] = acc[mi][ni][r] + bvv;
        }
      }
    }
    __syncthreads();
#pragma unroll
    for (int j = 0; j < 4; ++j) {
      const int u = j * 256 + t, row = u >> 5, c4 = (u & 31) * 4;
      *(float4*)(Of + (size_t)(m0 + p * 32 + row) * 768 + n0 + c4) =
          *(const float4*)(Lf + row * 132 + c4);
    }
  }
}

extern "C" void kernel_launch(void* const* d_in, const int* in_sizes, int n_in,
                              void* d_out, int out_size, void* d_ws, size_t ws_size,
                              hipStream_t stream) {
  (void)in_sizes; (void)n_in; (void)out_size; (void)ws_size;

  char* ws = (char*)d_ws;
  float* rl    = (float*)(ws + 4096);
  unsigned short* wcv = (unsigned short*)(ws + ((size_t)1 << 20));
  unsigned short* qb  = (unsigned short*)(ws + ((size_t)8  << 20));
  unsigned short* kb  = (unsigned short*)(ws + ((size_t)32 << 20));
  unsigned short* vt  = (unsigned short*)(ws + ((size_t)56 << 20));
  unsigned short* eb  = (unsigned short*)(ws + ((size_t)80 << 20));
  unsigned short* xb  = eb;     // converted x aliases E (x dead before score_k writes E)
  unsigned short* attn = qb;    // Q dead after score_k

  unsigned short* wqb = wcv;
  unsigned short* bqb = wcv + 589824;
  unsigned short* wkb = wcv + 590592;
  unsigned short* bkb = wcv + 1180416;
  unsigned short* wvb = wcv + 1181184;
  unsigned short* bvb = wcv + 1771008;
  unsigned short* wpb = wcv + 1771776;
  unsigned short* bpb = wcv + 2361600;

  const float inv_scale = 0.036084391824351615f;  // 1/sqrt(768)

  Cvt9 cv;
  cv.s[0] = d_in[0]; cv.d[0] = xb;  cv.n8[0] = 12582912 / 8;
  cv.s[1] = d_in[1]; cv.d[1] = wqb; cv.n8[1] = 589824 / 8;
  cv.s[2] = d_in[2]; cv.d[2] = bqb; cv.n8[2] = 768 / 8;
  cv.s[3] = d_in[3]; cv.d[3] = wkb; cv.n8[3] = 589824 / 8;
  cv.s[4] = d_in[4]; cv.d[4] = bkb; cv.n8[4] = 768 / 8;
  cv.s[5] = d_in[5]; cv.d[5] = wvb; cv.n8[5] = 589824 / 8;
  cv.s[6] = d_in[6]; cv.d[6] = bvb; cv.n8[6] = 768 / 8;
  cv.s[7] = d_in[7]; cv.d[7] = wpb; cv.n8[7] = 589824 / 8;
  cv.s[8] = d_in[8]; cv.d[8] = bpb; cv.n8[8] = 768 / 8;
  cv.total8 = (12582912 + 4 * (589824 + 768)) / 8;
  convert_inputs<<<(unsigned)((cv.total8 + 255) / 256), dim3(256), 0, stream>>>(cv);

  hipMemsetAsync(rl, 0, 16384 * sizeof(float), stream);

  qkv_k<<<dim3(128, 18, 1), dim3(256), 0, stream>>>(xb, wqb, bqb, wkb, bkb, wvb, bvb, qb, kb, vt);

  score_k<<<dim3(16, 16, 8), dim3(256), 0, stream>>>(qb, kb, eb, rl, inv_scale);

  pv_k<<<dim3(16, 6, 8), dim3(256), 0, stream>>>(eb, vt, rl, attn);

  out_k<<<dim3(128, 6, 1), dim3(256), 0, stream>>>(attn, wpb, bpb, (float*)d_out);
}

// Round 7
// 342.162 us; speedup vs baseline: 1.0290x; 1.0290x over previous
//
#include <hip/hip_runtime.h>
#include <stdint.h>

// MultiHeadAttention  B=8, S=2048, D=768  (fp32 in/out; bf16 MFMA compute)
//
// Pipeline:
//   convert : all 9 fp32 inputs -> bf16 in ws
//   qkv_k   : fused Q/K/V projections (grid 64x18, tile 256x128); Vt[b][e][s]
//   score_k : E = exp(min(Q.K^T/sqrt(D),30)) bf16 + fused rowsum -> rl
//   pv_k    : attn = (E @ V) * rcp(rl)
//   out_k   : out = attn@Wp^T + bp  (fp32)
//
// *** R7: staging-AI play: block 256x128, 8 waves, BK=32, fixed swizzle ***
// R6 datum: 38x bank-conflict swing (196K->7.57M) changed nothing -> LDS
// conflicts off the critical path. Cross-round model: delivered TF ~=
// staging_BW x block-tile-AI, with global_load_lds staging BW clustered at
// 10-14 TB/s (R6 10.4, m97 14, m201 12.2). 128^2 (AI=64) @10.4 => ~680 TF
// = observed. This round: AI 64 -> 85.3 (256x128) at 2-3 blocks/CU.
// Wave layout 4Mx2N (wave 64x64, acc[4][4] unchanged). BK=32 swizzle FIXED
// for the 64B-row bank alias: store k-chunk (t&3)^((t>>3)&3); read slot
// quad^((lo>>1)&3) -> with 16*(row&1) term: 8 bank-bases x 2 lanes = free.

typedef __attribute__((ext_vector_type(8))) short short8;
typedef __attribute__((ext_vector_type(4))) float f32x4;

typedef const __attribute__((address_space(1))) void gvoid_t;
typedef __attribute__((address_space(3))) void lvoid_t;

__device__ __forceinline__ float b2f(unsigned short u) {
  union { unsigned int u; float f; } v;
  v.u = ((unsigned int)u) << 16;
  return v.f;
}
__device__ __forceinline__ unsigned short f2b(float f) {
  union { float f; unsigned int u; } v; v.f = f;
  unsigned int u = v.u;
  return (unsigned short)((u + 0x7fffu + ((u >> 16) & 1u)) >> 16);
}

// ---------------- fp32 -> bf16 conversion ----------------
struct Cvt9 {
  const void* s[9];
  unsigned short* d[9];
  long long n8[9];
  long long total8;
};

__global__ __launch_bounds__(256) void convert_inputs(Cvt9 C) {
  long long g = (long long)blockIdx.x * 256 + threadIdx.x;
  if (g >= C.total8) return;
  int s = 0;
  long long off = g;
  while (off >= C.n8[s]) { off -= C.n8[s]; ++s; }
  const float* sf = (const float*)C.s[s] + off * 8;
  unsigned short* dp = C.d[s] + off * 8;
  float4 a = ((const float4*)sf)[0];
  float4 b = ((const float4*)sf)[1];
  uint4 o;
  o.x = (unsigned int)f2b(a.x) | ((unsigned int)f2b(a.y) << 16);
  o.y = (unsigned int)f2b(a.z) | ((unsigned int)f2b(a.w) << 16);
  o.z = (unsigned int)f2b(b.x) | ((unsigned int)f2b(b.y) << 16);
  o.w = (unsigned int)f2b(b.z) | ((unsigned int)f2b(b.w) << 16);
  *(uint4*)dp = o;
}

// ---------------- 256x128 / BK=32 GEMM core (8 waves, 4Mx2N) ----------------
// C[m0..+256][n0..+128] += A[m0..][0..K) . B[n0..][0..K)^T  (both NT-major, bf16)
// LDS buf b at b*24576 B: A 256x32 bf16 (16384 B), B 128x32 (8192 B).
// Row = 64 B = 4 slots of 16 B. Swizzle: phys slot s of row r holds k-chunk
// s^((r>>1)&3); staged via pre-swizzled global source; read slot =
// quad^((r>>1)&3). Bank base = 16*(r&1)+4*slot -> 8 bases x 2 lanes (free).
__device__ __forceinline__ void gemm256(
    const unsigned short* __restrict__ Ag,   // pre-offset to (m0, 0), lda shorts
    const unsigned short* __restrict__ Bg,   // pre-offset to (n0, 0), ldb shorts
    const int lda, const int ldb, const int NT,
    unsigned short* lds, f32x4 (&acc)[4][4])
{
  const int t    = threadIdx.x;      // 0..511
  const int w    = t >> 6;           // 0..7
  const int lane = t & 63;
  const int lo   = lane & 15;
  const int quad = lane >> 4;
  const int wr   = w >> 1;           // 0..3  row quarter (64 rows)
  const int wc   = w & 1;            // 0..1  col half (64 cols)
  const int srow = t >> 2;           // 0..127 staging row within unit
  const int ssw  = ((t & 3) ^ ((t >> 3) & 3)) << 3;   // pre-swizzled src k-slot (shorts)

  const unsigned lbase = (unsigned)(uintptr_t)(void*)lds;
  const unsigned rsw   = (unsigned)((quad ^ ((lo >> 1) & 3)) << 4);  // read slot (bytes)
  const unsigned aAr   = lbase + (unsigned)(wr * 64 + lo) * 64 + rsw;           // + mi*1024
  const unsigned aBr   = lbase + 16384u + (unsigned)(wc * 64 + lo) * 64 + rsw;  // + ni*1024

#define STG(kt, buf) {                                                              \
  const unsigned short* a0_ = Ag + (size_t)(srow)       * lda + (kt) * 32 + ssw;    \
  const unsigned short* a1_ = Ag + (size_t)(128 + srow) * lda + (kt) * 32 + ssw;    \
  const unsigned short* b0_ = Bg + (size_t)(srow)       * ldb + (kt) * 32 + ssw;    \
  unsigned short* d_ = lds + (buf) * 12288 + t * 8;                                 \
  __builtin_amdgcn_global_load_lds((gvoid_t*)a0_, (lvoid_t*)(d_),        16, 0, 0); \
  __builtin_amdgcn_global_load_lds((gvoid_t*)a1_, (lvoid_t*)(d_ + 4096), 16, 0, 0); \
  __builtin_amdgcn_global_load_lds((gvoid_t*)b0_, (lvoid_t*)(d_ + 8192), 16, 0, 0); }
#define DSR(d, a, IMM) asm volatile("ds_read_b128 %0, %1 offset:" #IMM : "=v"(d) : "v"(a))
#define LGK(n) { asm volatile("s_waitcnt lgkmcnt(" #n ")" ::: "memory"); \
                 __builtin_amdgcn_sched_barrier(0); }
#define GRP(g) { _Pragma("unroll") for (int mi = 0; mi < 4; ++mi)             \
    acc[mi][g] = __builtin_amdgcn_mfma_f32_16x16x32_bf16(                     \
        af[mi], bf[g], acc[mi][g], 0, 0, 0); }

  // prologue: stage tile 0 into buf 0
  STG(0, 0);
  __syncthreads();

  for (int kt = 0; kt < NT; ++kt) {
    const int buf = kt & 1;
    if (kt + 1 < NT) STG(kt + 1, buf ^ 1);

    const unsigned bo = (unsigned)(buf * 24576);
    short8 af[4], bf[4];
    const unsigned aA = aAr + bo, aB = aBr + bo;
    DSR(af[0], aA, 0); DSR(af[1], aA, 1024); DSR(af[2], aA, 2048); DSR(af[3], aA, 3072);
    DSR(bf[0], aB, 0); DSR(bf[1], aB, 1024); DSR(bf[2], aB, 2048); DSR(bf[3], aB, 3072);

    __builtin_amdgcn_s_setprio(1);
    LGK(3); GRP(0);
    LGK(2); GRP(1);
    LGK(1); GRP(2);
    LGK(0); GRP(3);
    __builtin_amdgcn_s_setprio(0);

    __syncthreads();   // drains vmcnt (tile kt+1 staged) + lgkm; barrier
  }
#undef STG
#undef DSR
#undef LGK
#undef GRP
}

// ---------------- bf16 epilogue: 256x128 tile via two 128-row LDS passes ----------------
// MODE 0: v += bias ; MODE 2: v = exp(min(v*scale,30)) [+rowsum] ; MODE 3: v *= rcp(rl[row])
template<int MODE>
__device__ __forceinline__ void epi_bf16(
    unsigned short* Ls, f32x4 (&acc)[4][4],
    const unsigned short* bias_n0, const float* rlbase, float scale,
    unsigned short* Cg, int ldc, float* rlout)
{
  const int t = threadIdx.x, w = t >> 6, lane = t & 63;
  const int lo = lane & 15, quad = lane >> 4, wr = w >> 1, wc = w & 1;
#pragma unroll
  for (int h = 0; h < 2; ++h) {
    __syncthreads();
    if ((wr >> 1) == h) {
      float bvv[4];
      if (MODE == 0) {
#pragma unroll
        for (int ni = 0; ni < 4; ++ni) bvv[ni] = b2f(bias_n0[wc * 64 + ni * 16 + lo]);
      }
#pragma unroll
      for (int mi = 0; mi < 4; ++mi) {
        const int r0 = (wr & 1) * 64 + mi * 16 + quad * 4;   // 0..127 within pass
        float rv[4];
        if (MODE == 3) {
#pragma unroll
          for (int r = 0; r < 4; ++r) rv[r] = __builtin_amdgcn_rcpf(rlbase[h * 128 + r0 + r]);
        }
#pragma unroll
        for (int ni = 0; ni < 4; ++ni) {
          const int col = wc * 64 + ni * 16 + lo;
#pragma unroll
          for (int r = 0; r < 4; ++r) {
            float v = acc[mi][ni][r];
            if (MODE == 0)      v += bvv[ni];
            else if (MODE == 2) v = __expf(fminf(v * scale, 30.f));
            else if (MODE == 3) v *= rv[r];
            Ls[(r0 + r) * 136 + col] = f2b(v);
          }
        }
      }
    }
    __syncthreads();
#pragma unroll
    for (int j = 0; j < 4; ++j) {
      const int u = j * 512 + t, row = u >> 4, c16 = (u & 15) * 8;
      *(uint4*)(Cg + (size_t)(h * 128 + row) * ldc + c16) = *(const uint4*)(Ls + row * 136 + c16);
    }
    if (MODE == 2) {
      // fused partial rowsum of this pass from LDS (4 threads/row, 32 cols each)
      const int row = t >> 2, seg = t & 3;
      const unsigned short* lr = Ls + row * 136 + seg * 32;
      float s = 0.f;
#pragma unroll
      for (int q4 = 0; q4 < 4; ++q4) {
        uint4 v = *(const uint4*)(lr + q4 * 8);
        unsigned int uu[4] = {v.x, v.y, v.z, v.w};
#pragma unroll
        for (int c = 0; c < 4; ++c)
          s += b2f((unsigned short)(uu[c] & 0xffffu)) + b2f((unsigned short)(uu[c] >> 16));
      }
      s += __shfl_xor(s, 1);
      s += __shfl_xor(s, 2);
      if (seg == 0) atomicAdd(rlout + h * 128 + row, s);
    }
  }
}

// ---------------- qkv: fused projections (tile 256x128) ----------------
__global__ __launch_bounds__(512, 4) void qkv_k(
    const unsigned short* __restrict__ xb,
    const unsigned short* __restrict__ Wq, const unsigned short* __restrict__ bq,
    const unsigned short* __restrict__ Wk, const unsigned short* __restrict__ bk,
    const unsigned short* __restrict__ Wv, const unsigned short* __restrict__ bv,
    unsigned short* __restrict__ qb, unsigned short* __restrict__ kb,
    unsigned short* __restrict__ vt)
{
  __shared__ unsigned short smem[24576];   // 49152 B
  const int sel = blockIdx.y / 6;
  const int n0  = (blockIdx.y % 6) * 128;
  const int m0  = blockIdx.x * 256;

  const unsigned short* W;
  const unsigned short* bi;
  if (sel == 0)      { W = Wq; bi = bq; }
  else if (sel == 1) { W = Wk; bi = bk; }
  else               { W = Wv; bi = bv; }

  f32x4 acc[4][4] = {};
  gemm256(xb + (size_t)m0 * 768, W + (size_t)n0 * 768, 768, 768, 24, smem, acc);

  if (sel < 2) {
    unsigned short* dst = (sel == 0 ? qb : kb) + (size_t)m0 * 768 + n0;
    epi_bf16<0>(smem, acc, bi + n0, nullptr, 0.f, dst, 768, nullptr);
    return;
  }

  // V: transposed epilogue into Vt[b][e][s]; 2 e-halves of 64, Ls [64][264]
  const int t = threadIdx.x, w = t >> 6, lane = t & 63;
  const int lo = lane & 15, quad = lane >> 4, wr = w >> 1, wc = w & 1;
  const int bb2 = m0 >> 11, sin = m0 & 2047;
  unsigned short* Ls = smem;
#pragma unroll
  for (int ec = 0; ec < 2; ++ec) {
    __syncthreads();
    if (wc == ec) {
#pragma unroll
      for (int ni = 0; ni < 4; ++ni) {
        const int el = ni * 16 + lo;
        const float bvv = b2f(bi[n0 + ec * 64 + el]);
#pragma unroll
        for (int mi = 0; mi < 4; ++mi) {
          const int sl = wr * 64 + mi * 16 + quad * 4;   // s within 256-row tile
          ushort4 pk;
          pk.x = f2b(acc[mi][ni][0] + bvv);
          pk.y = f2b(acc[mi][ni][1] + bvv);
          pk.z = f2b(acc[mi][ni][2] + bvv);
          pk.w = f2b(acc[mi][ni][3] + bvv);
          *(ushort4*)(Ls + el * 264 + sl) = pk;
        }
      }
    }
    __syncthreads();
    unsigned short* Vb = vt + (size_t)bb2 * 1572864 + (size_t)(n0 + ec * 64) * 2048 + sin;
#pragma unroll
    for (int j = 0; j < 4; ++j) {
      const int u = j * 512 + t, e = u >> 5, s16 = (u & 31) * 8;
      *(uint4*)(Vb + (size_t)e * 2048 + s16) = *(const uint4*)(Ls + e * 264 + s16);
    }
  }
}

// ---------------- score: E = exp(QK^T/sqrt(D)) + fused rowsum ----------------
__global__ __launch_bounds__(512, 4) void score_k(
    const unsigned short* __restrict__ Q, const unsigned short* __restrict__ Kb,
    unsigned short* __restrict__ E, float* __restrict__ rl, float scale)
{
  __shared__ unsigned short smem[24576];
  const int m0 = blockIdx.x * 256, n0 = blockIdx.y * 128, bz = blockIdx.z;

  f32x4 acc[4][4] = {};
  gemm256(Q + (size_t)bz * 1572864 + (size_t)m0 * 768,
          Kb + (size_t)bz * 1572864 + (size_t)n0 * 768, 768, 768, 24, smem, acc);

  unsigned short* Eg = E + (size_t)bz * 4194304 + (size_t)m0 * 2048 + n0;
  epi_bf16<2>(smem, acc, nullptr, nullptr, scale, Eg, 2048, rl + bz * 2048 + m0);
}

// ---------------- pv: attn = (E @ V) * rcp(rowsum) ----------------
__global__ __launch_bounds__(512, 4) void pv_k(
    const unsigned short* __restrict__ E, const unsigned short* __restrict__ Vt,
    const float* __restrict__ rl, unsigned short* __restrict__ attn)
{
  __shared__ unsigned short smem[24576];
  const int m0 = blockIdx.x * 256, n0 = blockIdx.y * 128, bz = blockIdx.z;

  f32x4 acc[4][4] = {};
  gemm256(E + (size_t)bz * 4194304 + (size_t)m0 * 2048,
          Vt + (size_t)bz * 1572864 + (size_t)n0 * 2048, 2048, 2048, 64, smem, acc);

  const float* rlb = rl + bz * 2048 + m0;
  unsigned short* Cg = attn + (size_t)bz * 1572864 + (size_t)m0 * 768 + n0;
  epi_bf16<3>(smem, acc, nullptr, rlb, 0.f, Cg, 768, nullptr);
}

// ---------------- out: final projection (fp32 output) ----------------
__global__ __launch_bounds__(512, 4) void out_k(
    const unsigned short* __restrict__ attn,
    const unsigned short* __restrict__ Wp, const unsigned short* __restrict__ bp,
    float* __restrict__ Of)
{
  __shared__ unsigned short smem[24576];
  const int m0 = blockIdx.x * 256, n0 = blockIdx.y * 128;

  f32x4 acc[4][4] = {};
  gemm256(attn + (size_t)m0 * 768, Wp + (size_t)n0 * 768, 768, 768, 24, smem, acc);

  // fp32 output: 4 passes of 64 rows staged as float through LDS [64][132]
  const int t = threadIdx.x, w = t >> 6, lane = t & 63;
  const int lo = lane & 15, quad = lane >> 4, wr = w >> 1, wc = w & 1;
  float* Lf = (float*)smem;
#pragma unroll
  for (int p = 0; p < 4; ++p) {
    __syncthreads();
    if (wr == p) {
#pragma unroll
      for (int mi = 0; mi < 4; ++mi) {
        const int r0 = mi * 16 + quad * 4;
#pragma unroll
        for (int ni = 0; ni < 4; ++ni) {
          const int col = wc * 64 + ni * 16 + lo;
          const float bvv = b2f(bp[n0 + col]);
#pragma unroll
          for (int r = 0; r < 4; ++r)
            Lf[(r0 + r) * 132 + col] = acc[mi][ni][r] + bvv;
        }
      }
    }
    __syncthreads();
#pragma unroll
    for (int j = 0; j < 2; ++j) {
      const int u = j * 512 + t, row = u >> 4, c4 = (u & 15) * 8;
      // 128 cols fp32 = 16 float8 per row -> use two float4 stores
      const float* src = Lf + row * 132 + c4;
      float4 v0 = *(const float4*)(src);
      float4 v1 = *(const float4*)(src + 4);
      float* dst = Of + (size_t)(m0 + p * 64 + row) * 768 + n0 + c4;
      *(float4*)(dst) = v0;
      *(float4*)(dst + 4) = v1;
    }
  }
}

extern "C" void kernel_launch(void* const* d_in, const int* in_sizes, int n_in,
                              void* d_out, int out_size, void* d_ws, size_t ws_size,
                              hipStream_t stream) {
  (void)in_sizes; (void)n_in; (void)out_size; (void)ws_size;

  char* ws = (char*)d_ws;
  float* rl    = (float*)(ws + 4096);
  unsigned short* wcv = (unsigned short*)(ws + ((size_t)1 << 20));
  unsigned short* qb  = (unsigned short*)(ws + ((size_t)8  << 20));
  unsigned short* kb  = (unsigned short*)(ws + ((size_t)32 << 20));
  unsigned short* vt  = (unsigned short*)(ws + ((size_t)56 << 20));
  unsigned short* eb  = (unsigned short*)(ws + ((size_t)80 << 20));
  unsigned short* xb  = eb;     // converted x aliases E (x dead before score_k writes E)
  unsigned short* attn = qb;    // Q dead after score_k

  unsigned short* wqb = wcv;
  unsigned short* bqb = wcv + 589824;
  unsigned short* wkb = wcv + 590592;
  unsigned short* bkb = wcv + 1180416;
  unsigned short* wvb = wcv + 1181184;
  unsigned short* bvb = wcv + 1771008;
  unsigned short* wpb = wcv + 1771776;
  unsigned short* bpb = wcv + 2361600;

  const float inv_scale = 0.036084391824351615f;  // 1/sqrt(768)

  Cvt9 cv;
  cv.s[0] = d_in[0]; cv.d[0] = xb;  cv.n8[0] = 12582912 / 8;
  cv.s[1] = d_in[1]; cv.d[1] = wqb; cv.n8[1] = 589824 / 8;
  cv.s[2] = d_in[2]; cv.d[2] = bqb; cv.n8[2] = 768 / 8;
  cv.s[3] = d_in[3]; cv.d[3] = wkb; cv.n8[3] = 589824 / 8;
  cv.s[4] = d_in[4]; cv.d[4] = bkb; cv.n8[4] = 768 / 8;
  cv.s[5] = d_in[5]; cv.d[5] = wvb; cv.n8[5] = 589824 / 8;
  cv.s[6] = d_in[6]; cv.d[6] = bvb; cv.n8[6] = 768 / 8;
  cv.s[7] = d_in[7]; cv.d[7] = wpb; cv.n8[7] = 589824 / 8;
  cv.s[8] = d_in[8]; cv.d[8] = bpb; cv.n8[8] = 768 / 8;
  cv.total8 = (12582912 + 4 * (589824 + 768)) / 8;
  convert_inputs<<<(unsigned)((cv.total8 + 255) / 256), dim3(256), 0, stream>>>(cv);

  hipMemsetAsync(rl, 0, 16384 * sizeof(float), stream);

  qkv_k<<<dim3(64, 18, 1), dim3(512), 0, stream>>>(xb, wqb, bqb, wkb, bkb, wvb, bvb, qb, kb, vt);

  score_k<<<dim3(8, 16, 8), dim3(512), 0, stream>>>(qb, kb, eb, rl, inv_scale);

  pv_k<<<dim3(8, 6, 8), dim3(512), 0, stream>>>(eb, vt, rl, attn);

  out_k<<<dim3(64, 6, 1), dim3(512), 0, stream>>>(attn, wpb, bpb, (float*)d_out);
}